// Round 20
// baseline (261.303 us; speedup 1.0000x reference)
//
#include <hip/hip_runtime.h>
#include <math.h>

#define D_MODEL 1024
#define D_INNER 2048
#define D_STATE 64
#define SEQ     2048
#define BATCH   2
#define NROWS   (BATCH*SEQ)   // 4096

typedef unsigned short ushort_t;
typedef unsigned int uint_t;
typedef __attribute__((ext_vector_type(8))) unsigned short ushort8_t;

__device__ __forceinline__ float silu_f(float x) { return x / (1.f + __expf(-x)); }
__device__ __forceinline__ ushort_t f2bf(float f) {
    uint_t u = __float_as_uint(f);
    uint_t r = (u + 0x7FFFu + ((u >> 16) & 1u)) >> 16;   // RNE
    return (ushort_t)r;
}
__device__ __forceinline__ float bf2f(ushort_t u) {
    return __uint_as_float(((uint_t)u) << 16);
}

typedef __attribute__((address_space(1))) const void gvoid_t;
typedef __attribute__((address_space(3))) void lvoid_t;

template<int N> __device__ __forceinline__ void wait_vmcnt() {
    if constexpr (N == 0)      asm volatile("s_waitcnt vmcnt(0)" ::: "memory");
    else if constexpr (N == 2) asm volatile("s_waitcnt vmcnt(2)" ::: "memory");
    else if constexpr (N == 3) asm volatile("s_waitcnt vmcnt(3)" ::: "memory");
    else if constexpr (N == 6) asm volatile("s_waitcnt vmcnt(6)" ::: "memory");
    else static_assert(N == 0, "unsupported vmcnt");
}

// ---------------------------------------------------------------------------
// Batched f32 -> bf16 conversion: 5 (src,dst) ranges in one launch.
// ---------------------------------------------------------------------------
__global__ __launch_bounds__(256) void cvt5_kernel(
    const float* __restrict__ s0, ushort_t* __restrict__ d0, int b0,
    const float* __restrict__ s1, ushort_t* __restrict__ d1, int b1,
    const float* __restrict__ s2, ushort_t* __restrict__ d2, int b2,
    const float* __restrict__ s3, ushort_t* __restrict__ d3, int b3,
    const float* __restrict__ s4, ushort_t* __restrict__ d4, int b4)
{
    int blk = blockIdx.x;
    const float* s; ushort_t* d;
    if (blk < b0)                    { s = s0; d = d0; }
    else if (blk < b0 + b1)          { s = s1; d = d1; blk -= b0; }
    else if (blk < b0 + b1 + b2)     { s = s2; d = d2; blk -= b0 + b1; }
    else if (blk < b0 + b1 + b2 + b3){ s = s3; d = d3; blk -= b0 + b1 + b2; }
    else                             { s = s4; d = d4; blk -= b0 + b1 + b2 + b3; }
    int i = (blk * 256 + threadIdx.x) * 4;
    float4 v = *reinterpret_cast<const float4*>(s + i);
    ushort4 o;
    o.x = f2bf(v.x); o.y = f2bf(v.y); o.z = f2bf(v.z); o.w = f2bf(v.w);
    *reinterpret_cast<ushort4*>(d + i) = o;
}

// ---------------------------------------------------------------------------
// GEMM body (8-wave 128x128, BK=32, depth-2 counted-vmcnt; r17-verified).
// Computes rows [bm,bm+128) x cols [bn,bn+128) of in_proj.  Epilogue:
// col<2048 -> bf16 x_ssm; col>=2048 -> bf16 silu(gate).
// ---------------------------------------------------------------------------
__device__ __forceinline__ void gemm128_body(
    const ushort_t* __restrict__ Abf, const ushort_t* __restrict__ Wbf,
    const float* __restrict__ bias,
    ushort_t* __restrict__ out_x, ushort_t* __restrict__ out_g,
    int bm, int bn, ushort_t* smem_u)
{
    using bf16x8 = __attribute__((ext_vector_type(8))) short;
    using f32x4  = __attribute__((ext_vector_type(4))) float;

    constexpr int K    = D_MODEL;
    constexpr int ABLK = 8;      // 128/16
    constexpr int NBLK = 16;
    constexpr int TILE = 8192;   // (128+128)*32 ushorts
    constexpr int L    = 2;      // NBLK/8

    ushort_t* buf0 = smem_u;
    ushort_t* buf1 = smem_u + TILE;

    const int tid  = threadIdx.x;
    const int lane = tid & 63;
    const int wid  = tid >> 6;
    const int wr   = (wid >> 2) * 64;      // 2 row groups
    const int wc   = (wid & 3) * 32;       // 4 col groups
    const int r16  = lane & 15;
    const int g    = lane >> 4;
    const int srow = lane >> 2;
    const int scg  = ((lane & 3) ^ (srow & 3)) * 8;
    const int rg   = (g ^ (r16 & 3)) * 8;

    f32x4 acc[4][2] = {};

    auto stage = [&](ushort_t* bufp, int k0) {
        #pragma unroll
        for (int i = wid; i < NBLK; i += 8) {
            const ushort_t* gsrc;
            if (i < ABLK)
                gsrc = Abf + (size_t)(bm + 16 * i + srow) * K + k0 + scg;
            else
                gsrc = Wbf + (size_t)(bn + 16 * (i - ABLK) + srow) * K + k0 + scg;
            __builtin_amdgcn_global_load_lds((gvoid_t*)gsrc, (lvoid_t*)(bufp + i * 512), 16, 0, 0);
        }
    };

    const int NT = K / 32;   // 32
    stage(buf0, 0);
    stage(buf1, 32);
    wait_vmcnt<L>();
    __builtin_amdgcn_s_barrier();

    for (int t = 0; t < NT; ++t) {
        const ushort_t* Tb = (t & 1) ? buf1 : buf0;
        bf16x8 af[4], bfr[2];
        #pragma unroll
        for (int m = 0; m < 4; ++m)
            af[m] = *reinterpret_cast<const bf16x8*>(
                &Tb[((wr >> 4) + m) * 512 + r16 * 32 + rg]);
        #pragma unroll
        for (int n = 0; n < 2; ++n)
            bfr[n] = *reinterpret_cast<const bf16x8*>(
                &Tb[(ABLK + (wc >> 4) + n) * 512 + r16 * 32 + rg]);

        asm volatile("s_waitcnt lgkmcnt(0)" ::: "memory");
        __builtin_amdgcn_s_barrier();

        if (t + 2 < NT) stage((t & 1) ? buf1 : buf0, (t + 2) * 32);

        #pragma unroll
        for (int m = 0; m < 4; ++m)
            #pragma unroll
            for (int n = 0; n < 2; ++n)
                acc[m][n] = __builtin_amdgcn_mfma_f32_16x16x32_bf16(af[m], bfr[n], acc[m][n], 0, 0, 0);

        if (t + 1 < NT) {
            if (t + 2 < NT) wait_vmcnt<L>();
            else            wait_vmcnt<0>();
            __builtin_amdgcn_s_barrier();
        }
    }

    #pragma unroll
    for (int m = 0; m < 4; ++m) {
        int row0 = bm + wr + m * 16 + g * 4;
        #pragma unroll
        for (int n = 0; n < 2; ++n) {
            int col = bn + wc + n * 16 + r16;
            float b = bias[col];
            if (col < D_INNER) {
                #pragma unroll
                for (int jj = 0; jj < 4; ++jj)
                    out_x[(size_t)(row0 + jj) * D_INNER + col] = f2bf(acc[m][n][jj] + b);
            } else {
                int c2 = col - D_INNER;
                #pragma unroll
                for (int jj = 0; jj < 4; ++jj)
                    out_g[(size_t)(row0 + jj) * D_INNER + c2] = f2bf(silu_f(acc[m][n][jj] + b));
            }
        }
    }
}

// ---------------------------------------------------------------------------
// in_proj x_ssm half: cols [0,2048), grid (16,32), 512 threads.
// ---------------------------------------------------------------------------
__global__ __launch_bounds__(512, 4) void gemm_x_half(
    const ushort_t* __restrict__ Abf, const ushort_t* __restrict__ Wbf,
    const float* __restrict__ bias,
    ushort_t* __restrict__ out_x, ushort_t* __restrict__ out_g)
{
    __shared__ ushort_t smem_u[16384];   // 32 KB
    gemm128_body(Abf, Wbf, bias, out_x, out_g,
                 blockIdx.y * 128, blockIdx.x * 128, smem_u);
}

// ---------------------------------------------------------------------------
// FUSED: gate-half GEMM (512 blocks, cols [2048,4096)) CONCURRENT WITH
// xbconv (64 blocks): conv+silu computed inline during xb's A-staging;
// writes xc (for ymul) and xb = xconv @ B^T.
// ---------------------------------------------------------------------------
#define NGEMM 512

__global__ __launch_bounds__(512, 4) void fused_gate_xbconv(
    const ushort_t* __restrict__ Abf, const ushort_t* __restrict__ Wbf,
    const float* __restrict__ bias,
    ushort_t* __restrict__ out_x, ushort_t* __restrict__ out_g,
    const ushort_t* __restrict__ xssm,
    const float* __restrict__ conv_w, const float* __restrict__ conv_b,
    const ushort_t* __restrict__ Bw,
    ushort_t* __restrict__ xc, float* __restrict__ xb)
{
    using bf16x8 = __attribute__((ext_vector_type(8))) short;
    using f32x4  = __attribute__((ext_vector_type(4))) float;

    __shared__ ushort_t smem_u[16384];   // 32 KB (gemm); xbconv uses 8 KB

    const int bid = blockIdx.x;
    if (bid < NGEMM) {
        // gate half: bn in [2048, 4096)
        const int bm = (bid >> 4) * 128;
        const int bn = D_INNER + (bid & 15) * 128;
        gemm128_body(Abf, Wbf, bias, out_x, out_g, bm, bn, smem_u);
        return;
    }

    // ---- xbconv path: 64 blocks, 64 rows each, 8 waves ----
    const int bm   = (bid - NGEMM) * 64;
    const int tid  = threadIdx.x;
    const int lane = tid & 63;
    const int w    = tid >> 6;
    const int wr2  = w >> 1;          // 0..3  (16-row group)
    const int wc2  = w & 1;           // 0..1  (32-col group)
    const int r16  = lane & 15;
    const int g    = lane >> 4;

    ushort_t* As = smem_u;            // [64][32] row-major
    ushort_t* Bs = smem_u + 2048;     // [64][32] row-major

    const bool isA = (tid < 256);
    const int rl = (isA ? tid : tid - 256) >> 2;          // row_local 0..63
    const int ck = ((isA ? tid : tid - 256) & 3) * 8;     // channel chunk

    const int row = bm + rl;
    const int s   = row & (SEQ - 1);

    f32x4 acc[2] = {};

    for (int k0 = 0; k0 < D_INNER; k0 += 32) {
        if (isA) {
            const int c0 = k0 + ck;
            // load current + 3 halo rows (8 channels each); zero invalid taps
            float xr[4][8];
            #pragma unroll
            for (int dt = 0; dt < 4; ++dt) {
                if (dt == 0 || s >= dt) {
                    ushort8_t v = *reinterpret_cast<const ushort8_t*>(
                        xssm + (size_t)(row - dt) * D_INNER + c0);
                    #pragma unroll
                    for (int j = 0; j < 8; ++j) xr[dt][j] = bf2f(v[j]);
                } else {
                    #pragma unroll
                    for (int j = 0; j < 8; ++j) xr[dt][j] = 0.f;
                }
            }
            ushort8_t h;
            #pragma unroll
            for (int j = 0; j < 8; ++j) {
                const float* wv = conv_w + (c0 + j) * 4;
                float a = conv_b[c0 + j];
                a += wv[3] * xr[0][j];       // dt=0, weight idx 3
                a += wv[2] * xr[1][j];       // dt=1
                a += wv[1] * xr[2][j];       // dt=2
                a += wv[0] * xr[3][j];       // dt=3
                h[j] = f2bf(silu_f(a));
            }
            *reinterpret_cast<ushort8_t*>(As + rl * 32 + ck) = h;                       // LDS
            *reinterpret_cast<ushort8_t*>(xc + (size_t)row * D_INNER + c0) = h;          // global
        } else {
            const ushort_t* gsrc = Bw + (size_t)rl * D_INNER + k0 + ck;
            __builtin_amdgcn_global_load_lds((gvoid_t*)gsrc,
                (lvoid_t*)(Bs + (tid - 256) * 8), 16, 0, 0);
        }
        __syncthreads();

        bf16x8 a = *reinterpret_cast<const bf16x8*>(&As[(wr2 * 16 + r16) * 32 + g * 8]);
        #pragma unroll
        for (int n = 0; n < 2; ++n) {
            bf16x8 bv = *reinterpret_cast<const bf16x8*>(
                &Bs[(wc2 * 32 + n * 16 + r16) * 32 + g * 8]);
            acc[n] = __builtin_amdgcn_mfma_f32_16x16x32_bf16(a, bv, acc[n], 0, 0, 0);
        }
        __syncthreads();
    }

    #pragma unroll
    for (int n = 0; n < 2; ++n) {
        int col  = wc2 * 32 + n * 16 + r16;
        int row0 = bm + wr2 * 16 + g * 4;
        #pragma unroll
        for (int jj = 0; jj < 4; ++jj)
            xb[(size_t)(row0 + jj) * D_STATE + col] = acc[n][jj];
    }
}

// ---------------------------------------------------------------------------
// out_proj GEMM: 256-thread depth-2, KH=2, XCD-chunk swizzle (r18 proven).
// ---------------------------------------------------------------------------
template <int BMt, int BNt, int KH>
__global__ __launch_bounds__(256) void gemm_pipe(
    const ushort_t* __restrict__ Abf, const ushort_t* __restrict__ Wbf,
    const float* __restrict__ bias,
    float* __restrict__ out0, int M, int N, int K)
{
    using bf16x8 = __attribute__((ext_vector_type(8))) short;
    using f32x4  = __attribute__((ext_vector_type(4))) float;

    constexpr int BKt  = 32 * KH;
    constexpr int MF   = BMt / 32;
    constexpr int NF   = BNt / 32;
    constexpr int ARB  = BMt / 16;
    constexpr int BRB  = BNt / 16;
    constexpr int ABLK = ARB * KH;
    constexpr int NBLK = (ARB + BRB) * KH;
    constexpr int TILE = (BMt + BNt) * BKt;
    constexpr int L    = NBLK / 4;

    __shared__ ushort_t buf[2][TILE];

    const int tid  = threadIdx.x;
    const int lane = tid & 63;
    const int wid  = tid >> 6;

    const int nbn  = N / BNt;
    const int bid  = blockIdx.x;
    const int nb   = (M / BMt) * nbn;
    const int cpx  = nb / 8;
    const int flat = (bid & 7) * cpx + (bid >> 3);
    const int bm   = (flat / nbn) * BMt;
    const int bn   = (flat % nbn) * BNt;

    const int wr   = (wid >> 1) * (BMt / 2);
    const int wc   = (wid & 1) * (BNt / 2);
    const int r16  = lane & 15;
    const int g    = lane >> 4;
    const int srow = lane >> 2;
    const int scg  = ((lane & 3) ^ (srow & 3)) * 8;
    const int rg   = (g ^ (r16 & 3)) * 8;

    f32x4 acc[MF][NF] = {};

    auto stage = [&](int p, int k0) {
        #pragma unroll
        for (int i = wid; i < NBLK; i += 4) {
            const ushort_t* gsrc;
            if (i < ABLK) {
                int kh = i / ARB, rb = i % ARB;
                gsrc = Abf + (size_t)(bm + 16 * rb + srow) * K + k0 + kh * 32 + scg;
            } else {
                int j = i - ABLK;
                int kh = j / BRB, rb = j % BRB;
                gsrc = Wbf + (size_t)(bn + 16 * rb + srow) * K + k0 + kh * 32 + scg;
            }
            __builtin_amdgcn_global_load_lds((gvoid_t*)gsrc, (lvoid_t*)(&buf[p][i * 512]), 16, 0, 0);
        }
    };

    const int NT = K / BKt;
    stage(0, 0);
    stage(1, BKt);
    wait_vmcnt<L>();
    __builtin_amdgcn_s_barrier();

    for (int t = 0; t < NT; ++t) {
        const ushort_t* Tb = &buf[t & 1][0];
        bf16x8 af[MF][KH], bfr[NF][KH];
        #pragma unroll
        for (int kk = 0; kk < KH; ++kk) {
            #pragma unroll
            for (int m = 0; m < MF; ++m)
                af[m][kk] = *reinterpret_cast<const bf16x8*>(
                    &Tb[(kk * ARB + (wr >> 4) + m) * 512 + r16 * 32 + rg]);
            #pragma unroll
            for (int n = 0; n < NF; ++n)
                bfr[n][kk] = *reinterpret_cast<const bf16x8*>(
                    &Tb[(ABLK + kk * BRB + (wc >> 4) + n) * 512 + r16 * 32 + rg]);
        }

        asm volatile("s_waitcnt lgkmcnt(0)" ::: "memory");
        __builtin_amdgcn_s_barrier();

        if (t + 2 < NT) stage(t & 1, (t + 2) * BKt);

        #pragma unroll
        for (int kk = 0; kk < KH; ++kk)
            #pragma unroll
            for (int m = 0; m < MF; ++m)
                #pragma unroll
                for (int n = 0; n < NF; ++n)
                    acc[m][n] = __builtin_amdgcn_mfma_f32_16x16x32_bf16(
                        af[m][kk], bfr[n][kk], acc[m][n], 0, 0, 0);

        if (t + 1 < NT) {
            if (t + 2 < NT) wait_vmcnt<L>();
            else            wait_vmcnt<0>();
            __builtin_amdgcn_s_barrier();
        }
    }

    #pragma unroll
    for (int m = 0; m < MF; ++m) {
        int row0 = bm + wr + m * 16 + g * 4;
        #pragma unroll
        for (int n = 0; n < NF; ++n) {
            int col = bn + wc + n * 16 + r16;
            float b = bias[col];
            #pragma unroll
            for (int jj = 0; jj < 4; ++jj)
                out0[(size_t)(row0 + jj) * N + col] = acc[m][n][jj] + b;
        }
    }
}

// ---------------------------------------------------------------------------
// Speculative chunked tanh scan (overlap-save), C=W=32.  Emits bf16 H.
// ---------------------------------------------------------------------------
#define SCAN_C 32
#define SCAN_W 32
#define NCHUNK (SEQ / SCAN_C)   // 64

__global__ __launch_bounds__(64) void scan_kernel(const float* __restrict__ xb,
                                                  const float* __restrict__ A,
                                                  ushort_t* __restrict__ hall)
{
    using f32x4 = __attribute__((ext_vector_type(4))) float;

    __shared__ float xs[(SCAN_C + SCAN_W) * D_STATE];   // 16 KB
    __shared__ float hs[D_STATE];

    const int blk = blockIdx.x;
    const int b = blk >> 6;
    const int c = blk & (NCHUNK - 1);
    const int j = threadIdx.x;

    const int t0     = (c == 0) ? 0 : (c * SCAN_C - SCAN_W);
    const int warm   = c * SCAN_C - t0;        // 0 or 32
    const int nsteps = warm + SCAN_C;          // 32 or 64

    f32x4 areg[16];
    {
        const f32x4* arow = reinterpret_cast<const f32x4*>(A + j * D_STATE);
        #pragma unroll
        for (int q = 0; q < 16; ++q) areg[q] = arow[q];
    }

    const float* src = xb   + ((size_t)b * SEQ + t0) * D_STATE;
    ushort_t*    dst = hall + ((size_t)b * SEQ + c * SCAN_C) * D_STATE;

    const int nld = nsteps * D_STATE / 256;
    for (int i = 0; i < nld; ++i)
        __builtin_amdgcn_global_load_lds((gvoid_t*)(src + i * 256 + j * 4),
                                         (lvoid_t*)(&xs[i * 256]), 16, 0, 0);
    asm volatile("s_waitcnt vmcnt(0)" ::: "memory");

    hs[j] = 0.f;
    float h = 0.f;
    const f32x4* hp = reinterpret_cast<const f32x4*>(hs);

#define SCAN_STEP(t)                                                     \
    {                                                                    \
        float xv = xs[(t) * D_STATE + j];                                \
        f32x4 a0 = {xv, 0.f, 0.f, 0.f}, a1 = {0.f, 0.f, 0.f, 0.f};      \
        _Pragma("unroll")                                                \
        for (int q = 0; q < 16; q += 2) {                                \
            a0 += areg[q + 0] * hp[q + 0];                               \
            a1 += areg[q + 1] * hp[q + 1];                               \
        }                                                                \
        f32x4 s4 = a0 + a1;                                              \
        float s = (s4[0] + s4[1]) + (s4[2] + s4[3]);                     \
        float e = __expf(2.f * s);                                       \
        h = 1.f - 2.f * __builtin_amdgcn_rcpf(e + 1.f);                  \
        hs[j] = h;                                                       \
    }

    for (int t = 0; t < warm; ++t) {
        SCAN_STEP(t);
    }
    for (int t = warm; t < nsteps; ++t) {
        SCAN_STEP(t);
        dst[(size_t)(t - warm) * D_STATE + j] = f2bf(h);
    }
#undef SCAN_STEP
}

// ---------------------------------------------------------------------------
// ymul via MFMA: Y = H(4096x64) @ C(2048x64)^T, fused epilogue (r16 proven).
// ---------------------------------------------------------------------------
__global__ __launch_bounds__(256) void ymul_mfma(
    const ushort_t* __restrict__ Hbf,
    const ushort_t* __restrict__ Cbf,
    const float* __restrict__ Dv,
    const ushort_t* __restrict__ xc,
    const ushort_t* __restrict__ xg,
    ushort_t* __restrict__ xout)
{
    using bf16x8 = __attribute__((ext_vector_type(8))) short;
    using f32x4  = __attribute__((ext_vector_type(4))) float;

    constexpr int ARB  = 8;
    constexpr int ABLK = 16;
    constexpr int NBLK = 32;

    __shared__ ushort_t Tb[NBLK * 512];   // 32 KB

    const int tid  = threadIdx.x;
    const int lane = tid & 63;
    const int wid  = tid >> 6;
    const int bm   = blockIdx.y * 128;
    const int bn   = blockIdx.x * 128;
    const int wr   = (wid >> 1) * 64;
    const int wc   = (wid & 1) * 64;
    const int r16  = lane & 15;
    const int g    = lane >> 4;
    const int srow = lane >> 2;
    const int scg  = ((lane & 3) ^ (srow & 3)) * 8;
    const int rg   = (g ^ (r16 & 3)) * 8;

    #pragma unroll
    for (int i = wid; i < NBLK; i += 4) {
        const ushort_t* gsrc;
        if (i < ABLK) {
            int kh = i / ARB, rb = i % ARB;
            gsrc = Hbf + (size_t)(bm + 16 * rb + srow) * D_STATE + kh * 32 + scg;
        } else {
            int j = i - ABLK;
            int kh = j / ARB, rb = j % ARB;
            gsrc = Cbf + (size_t)(bn + 16 * rb + srow) * D_STATE + kh * 32 + scg;
        }
        __builtin_amdgcn_global_load_lds((gvoid_t*)gsrc, (lvoid_t*)(&Tb[i * 512]), 16, 0, 0);
    }
    __syncthreads();

    f32x4 acc[4][4] = {};
    bf16x8 af[4][2], bfr[4][2];
    #pragma unroll
    for (int kk = 0; kk < 2; ++kk) {
        #pragma unroll
        for (int m = 0; m < 4; ++m)
            af[m][kk] = *reinterpret_cast<const bf16x8*>(
                &Tb[(kk * ARB + (wr >> 4) + m) * 512 + r16 * 32 + rg]);
        #pragma unroll
        for (int n = 0; n < 4; ++n)
            bfr[n][kk] = *reinterpret_cast<const bf16x8*>(
                &Tb[(ABLK + kk * ARB + (wc >> 4) + n) * 512 + r16 * 32 + rg]);
    }
    #pragma unroll
    for (int kk = 0; kk < 2; ++kk)
        #pragma unroll
        for (int m = 0; m < 4; ++m)
            #pragma unroll
            for (int n = 0; n < 4; ++n)
                acc[m][n] = __builtin_amdgcn_mfma_f32_16x16x32_bf16(
                    af[m][kk], bfr[n][kk], acc[m][n], 0, 0, 0);

    #pragma unroll
    for (int m = 0; m < 4; ++m) {
        int row0 = bm + wr + m * 16 + g * 4;
        #pragma unroll
        for (int n = 0; n < 4; ++n) {
            int col = bn + wc + n * 16 + r16;
            float dv = Dv[col];
            #pragma unroll
            for (int jj = 0; jj < 4; ++jj) {
                size_t idx = (size_t)(row0 + jj) * D_INNER + col;
                float y = acc[m][n][jj] + bf2f(xc[idx]) * dv;
                xout[idx] = f2bf(y * bf2f(xg[idx]));
            }
        }
    }
}

// ---------------------------------------------------------------------------
extern "C" void kernel_launch(void* const* d_in, const int* in_sizes, int n_in,
                              void* d_out, int out_size, void* d_ws, size_t ws_size,
                              hipStream_t stream)
{
    const float* x          = (const float*)d_in[0];
    const float* in_proj_w  = (const float*)d_in[1];
    const float* in_proj_b  = (const float*)d_in[2];
    const float* conv_w     = (const float*)d_in[3];
    const float* conv_b     = (const float*)d_in[4];
    const float* A          = (const float*)d_in[5];
    const float* B          = (const float*)d_in[6];
    const float* C          = (const float*)d_in[7];
    const float* D          = (const float*)d_in[8];
    const float* out_proj_w = (const float*)d_in[9];
    const float* out_proj_b = (const float*)d_in[10];
    float* out = (float*)d_out;

    char* ws = (char*)d_ws;
    ushort_t* xg_bf   = (ushort_t*)(ws + 0);             // 16,777,216
    ushort_t* xc_bf   = (ushort_t*)(ws + 16777216);      // 16,777,216
    ushort_t* xssm_bf = (ushort_t*)(ws + 33554432);      // 16,777,216
    ushort_t* x_bf    = (ushort_t*)(ws + 50331648);      //  8,388,608 (dead after fused)
    ushort_t* w1_bf   = (ushort_t*)(ws + 58720256);      //  8,388,608 (dead after fused)
    ushort_t* xout_bf = (ushort_t*)(ws + 50331648);      // 16,777,216 (reuses x_bf+w1_bf)
    ushort_t* w2_bf   = (ushort_t*)(ws + 67108864);      //  4,194,304
    ushort_t* B_bf    = (ushort_t*)(ws + 71303168);      //    262,144
    float*    xb      = (float*)(ws + 71565312);         //  1,048,576
    ushort_t* hall_bf = (ushort_t*)(ws + 72613888);      //    524,288
    ushort_t* C_bf    = (ushort_t*)(ws + 73138176);      //    262,144

    // 1. all f32 -> bf16 conversions, one launch (x, w1, w2, B, C)
    {
        int b0 = NROWS * D_MODEL / 1024;           // 4096
        int b1 = 2 * D_INNER * D_MODEL / 1024;     // 4096
        int b2 = D_MODEL * D_INNER / 1024;         // 2048
        int b3 = D_STATE * D_INNER / 1024;         // 128
        int b4 = D_INNER * D_STATE / 1024;         // 128
        cvt5_kernel<<<b0 + b1 + b2 + b3 + b4, 256, 0, stream>>>(
            x, x_bf, b0, in_proj_w, w1_bf, b1, out_proj_w, w2_bf, b2,
            B, B_bf, b3, C, C_bf, b4);
    }
    // 2. in_proj x_ssm half (cols 0:2048), 8-wave 128x128, 512 blocks
    {
        dim3 grid(D_INNER / 128, NROWS / 128);
        gemm_x_half<<<grid, 512, 0, stream>>>(x_bf, w1_bf, in_proj_b, xssm_bf, xg_bf);
    }
    // 3. FUSED: gate half GEMM (512 blocks) || conv+xb (64 blocks)
    fused_gate_xbconv<<<NGEMM + NROWS / 64, 512, 0, stream>>>(
        x_bf, w1_bf, in_proj_b, xssm_bf, xg_bf,
        xssm_bf, conv_w, conv_b, B_bf, xc_bf, xb);
    // 4. speculative chunked scan (C=W=32) -> bf16 H
    scan_kernel<<<BATCH * NCHUNK, 64, 0, stream>>>(xb, A, hall_bf);
    // 5. ymul via MFMA (fused D-skip + gate) -> bf16 x_out
    {
        dim3 grid(D_INNER / 128, NROWS / 128);
        ymul_mfma<<<grid, 256, 0, stream>>>(hall_bf, C_bf, D, xc_bf, xg_bf, xout_bf);
    }
    // 6. out_proj GEMM (256-thread 128x64 KH=2, XCD-chunked)
    gemm_pipe<128, 64, 2><<<(NROWS / 128) * (D_MODEL / 64), 256, 0, stream>>>(
        xout_bf, w2_bf, out_proj_b, out, NROWS, D_MODEL, D_INNER);
}

// Round 21
// 148.117 us; speedup vs baseline: 1.7642x; 1.7642x over previous
//
#include <hip/hip_runtime.h>
#include <math.h>

#define D_MODEL 1024
#define D_INNER 2048
#define D_STATE 64
#define SEQ     2048
#define BATCH   2
#define NROWS   (BATCH*SEQ)   // 4096

typedef unsigned short ushort_t;
typedef unsigned int uint_t;

__device__ __forceinline__ float silu_f(float x) { return x / (1.f + __expf(-x)); }
__device__ __forceinline__ ushort_t f2bf(float f) {
    uint_t u = __float_as_uint(f);
    uint_t r = (u + 0x7FFFu + ((u >> 16) & 1u)) >> 16;   // RNE
    return (ushort_t)r;
}
__device__ __forceinline__ float bf2f(ushort_t u) {
    return __uint_as_float(((uint_t)u) << 16);
}

typedef __attribute__((address_space(1))) const void gvoid_t;
typedef __attribute__((address_space(3))) void lvoid_t;

template<int N> __device__ __forceinline__ void wait_vmcnt() {
    if constexpr (N == 0)      asm volatile("s_waitcnt vmcnt(0)" ::: "memory");
    else if constexpr (N == 3) asm volatile("s_waitcnt vmcnt(3)" ::: "memory");
    else if constexpr (N == 6) asm volatile("s_waitcnt vmcnt(6)" ::: "memory");
    else static_assert(N == 0, "unsupported vmcnt");
}

// ---------------------------------------------------------------------------
// Batched f32 -> bf16 conversion: 5 (src,dst) ranges in one launch.
// ---------------------------------------------------------------------------
__global__ __launch_bounds__(256) void cvt5_kernel(
    const float* __restrict__ s0, ushort_t* __restrict__ d0, int b0,
    const float* __restrict__ s1, ushort_t* __restrict__ d1, int b1,
    const float* __restrict__ s2, ushort_t* __restrict__ d2, int b2,
    const float* __restrict__ s3, ushort_t* __restrict__ d3, int b3,
    const float* __restrict__ s4, ushort_t* __restrict__ d4, int b4)
{
    int blk = blockIdx.x;
    const float* s; ushort_t* d;
    if (blk < b0)                    { s = s0; d = d0; }
    else if (blk < b0 + b1)          { s = s1; d = d1; blk -= b0; }
    else if (blk < b0 + b1 + b2)     { s = s2; d = d2; blk -= b0 + b1; }
    else if (blk < b0 + b1 + b2 + b3){ s = s3; d = d3; blk -= b0 + b1 + b2; }
    else                             { s = s4; d = d4; blk -= b0 + b1 + b2 + b3; }
    int i = (blk * 256 + threadIdx.x) * 4;
    float4 v = *reinterpret_cast<const float4*>(s + i);
    ushort4 o;
    o.x = f2bf(v.x); o.y = f2bf(v.y); o.z = f2bf(v.z); o.w = f2bf(v.w);
    *reinterpret_cast<ushort4*>(d + i) = o;
}

// ---------------------------------------------------------------------------
// in_proj GEMM: 8-wave 256x128 depth-2, 2-D raster (r16/r19 measured-best).
// ---------------------------------------------------------------------------
__global__ __launch_bounds__(512, 4) void gemm_pipe8_inproj(
    const ushort_t* __restrict__ Abf, const ushort_t* __restrict__ Wbf,
    const float* __restrict__ bias,
    ushort_t* __restrict__ out_x, ushort_t* __restrict__ out_g, int K)
{
    using bf16x8 = __attribute__((ext_vector_type(8))) short;
    using f32x4  = __attribute__((ext_vector_type(4))) float;

    constexpr int BMt  = 256, BNt = 128, BKt = 32;
    constexpr int ABLK = BMt / 16;            // 16
    constexpr int NBLK = (BMt + BNt) / 16;    // 24
    constexpr int TILE = (BMt + BNt) * BKt;   // 24KB
    constexpr int L    = NBLK / 8;            // 3

    __shared__ ushort_t buf[2][TILE];

    const int tid  = threadIdx.x;
    const int lane = tid & 63;
    const int wid  = tid >> 6;
    const int bm   = blockIdx.y * BMt;
    const int bn   = blockIdx.x * BNt;
    const int wr   = (wid >> 1) * 64;
    const int wc   = (wid & 1) * 64;
    const int r16  = lane & 15;
    const int g    = lane >> 4;
    const int srow = lane >> 2;
    const int scg  = ((lane & 3) ^ (srow & 3)) * 8;
    const int rg   = (g ^ (r16 & 3)) * 8;

    f32x4 acc[4][4] = {};

    auto stage = [&](int p, int k0) {
        #pragma unroll
        for (int i = wid; i < NBLK; i += 8) {
            const ushort_t* gsrc;
            if (i < ABLK)
                gsrc = Abf + (size_t)(bm + 16 * i + srow) * K + k0 + scg;
            else
                gsrc = Wbf + (size_t)(bn + 16 * (i - ABLK) + srow) * K + k0 + scg;
            __builtin_amdgcn_global_load_lds((gvoid_t*)gsrc, (lvoid_t*)(&buf[p][i * 512]), 16, 0, 0);
        }
    };

    const int NT = K / BKt;
    stage(0, 0);
    stage(1, BKt);
    wait_vmcnt<L>();
    __builtin_amdgcn_s_barrier();

    for (int t = 0; t < NT; ++t) {
        const ushort_t* Tb = &buf[t & 1][0];
        bf16x8 af[4], bfr[4];
        #pragma unroll
        for (int m = 0; m < 4; ++m)
            af[m] = *reinterpret_cast<const bf16x8*>(
                &Tb[((wr >> 4) + m) * 512 + r16 * 32 + rg]);
        #pragma unroll
        for (int n = 0; n < 4; ++n)
            bfr[n] = *reinterpret_cast<const bf16x8*>(
                &Tb[(ABLK + (wc >> 4) + n) * 512 + r16 * 32 + rg]);

        asm volatile("s_waitcnt lgkmcnt(0)" ::: "memory");
        __builtin_amdgcn_s_barrier();

        if (t + 2 < NT) stage(t & 1, (t + 2) * BKt);

        #pragma unroll
        for (int m = 0; m < 4; ++m)
            #pragma unroll
            for (int n = 0; n < 4; ++n)
                acc[m][n] = __builtin_amdgcn_mfma_f32_16x16x32_bf16(af[m], bfr[n], acc[m][n], 0, 0, 0);

        if (t + 1 < NT) {
            if (t + 2 < NT) wait_vmcnt<L>();
            else            wait_vmcnt<0>();
            __builtin_amdgcn_s_barrier();
        }
    }

    #pragma unroll
    for (int m = 0; m < 4; ++m) {
        int row0 = bm + wr + m * 16 + g * 4;
        #pragma unroll
        for (int n = 0; n < 4; ++n) {
            int col = bn + wc + n * 16 + r16;
            float b = bias[col];
            if (col < D_INNER) {
                #pragma unroll
                for (int jj = 0; jj < 4; ++jj)
                    out_x[(size_t)(row0 + jj) * D_INNER + col] = f2bf(acc[m][n][jj] + b);
            } else {
                int c2 = col - D_INNER;
                #pragma unroll
                for (int jj = 0; jj < 4; ++jj)
                    out_g[(size_t)(row0 + jj) * D_INNER + c2] = f2bf(silu_f(acc[m][n][jj] + b));
            }
        }
    }
}

// ---------------------------------------------------------------------------
// out_proj GEMM: 256-thread depth-2, KH=2, XCD-chunk swizzle (r18 proven).
// ---------------------------------------------------------------------------
template <int BMt, int BNt, int KH>
__global__ __launch_bounds__(256) void gemm_pipe(
    const ushort_t* __restrict__ Abf, const ushort_t* __restrict__ Wbf,
    const float* __restrict__ bias,
    float* __restrict__ out0, int M, int N, int K)
{
    using bf16x8 = __attribute__((ext_vector_type(8))) short;
    using f32x4  = __attribute__((ext_vector_type(4))) float;

    constexpr int BKt  = 32 * KH;
    constexpr int MF   = BMt / 32;
    constexpr int NF   = BNt / 32;
    constexpr int ARB  = BMt / 16;
    constexpr int BRB  = BNt / 16;
    constexpr int ABLK = ARB * KH;
    constexpr int NBLK = (ARB + BRB) * KH;
    constexpr int TILE = (BMt + BNt) * BKt;
    constexpr int L    = NBLK / 4;

    __shared__ ushort_t buf[2][TILE];

    const int tid  = threadIdx.x;
    const int lane = tid & 63;
    const int wid  = tid >> 6;

    // XCD-chunk swizzle over M/BMt x N/BNt grid (1-D launch)
    const int nbn  = N / BNt;
    const int bid  = blockIdx.x;
    const int nb   = (M / BMt) * nbn;
    const int cpx  = nb / 8;
    const int flat = (bid & 7) * cpx + (bid >> 3);
    const int bm   = (flat / nbn) * BMt;
    const int bn   = (flat % nbn) * BNt;

    const int wr   = (wid >> 1) * (BMt / 2);
    const int wc   = (wid & 1) * (BNt / 2);
    const int r16  = lane & 15;
    const int g    = lane >> 4;
    const int srow = lane >> 2;
    const int scg  = ((lane & 3) ^ (srow & 3)) * 8;
    const int rg   = (g ^ (r16 & 3)) * 8;

    f32x4 acc[MF][NF] = {};

    auto stage = [&](int p, int k0) {
        #pragma unroll
        for (int i = wid; i < NBLK; i += 4) {
            const ushort_t* gsrc;
            if (i < ABLK) {
                int kh = i / ARB, rb = i % ARB;
                gsrc = Abf + (size_t)(bm + 16 * rb + srow) * K + k0 + kh * 32 + scg;
            } else {
                int j = i - ABLK;
                int kh = j / BRB, rb = j % BRB;
                gsrc = Wbf + (size_t)(bn + 16 * rb + srow) * K + k0 + kh * 32 + scg;
            }
            __builtin_amdgcn_global_load_lds((gvoid_t*)gsrc, (lvoid_t*)(&buf[p][i * 512]), 16, 0, 0);
        }
    };

    const int NT = K / BKt;
    stage(0, 0);
    stage(1, BKt);
    wait_vmcnt<L>();
    __builtin_amdgcn_s_barrier();

    for (int t = 0; t < NT; ++t) {
        const ushort_t* Tb = &buf[t & 1][0];
        bf16x8 af[MF][KH], bfr[NF][KH];
        #pragma unroll
        for (int kk = 0; kk < KH; ++kk) {
            #pragma unroll
            for (int m = 0; m < MF; ++m)
                af[m][kk] = *reinterpret_cast<const bf16x8*>(
                    &Tb[(kk * ARB + (wr >> 4) + m) * 512 + r16 * 32 + rg]);
            #pragma unroll
            for (int n = 0; n < NF; ++n)
                bfr[n][kk] = *reinterpret_cast<const bf16x8*>(
                    &Tb[(ABLK + kk * BRB + (wc >> 4) + n) * 512 + r16 * 32 + rg]);
        }

        asm volatile("s_waitcnt lgkmcnt(0)" ::: "memory");
        __builtin_amdgcn_s_barrier();

        if (t + 2 < NT) stage(t & 1, (t + 2) * BKt);

        #pragma unroll
        for (int kk = 0; kk < KH; ++kk)
            #pragma unroll
            for (int m = 0; m < MF; ++m)
                #pragma unroll
                for (int n = 0; n < NF; ++n)
                    acc[m][n] = __builtin_amdgcn_mfma_f32_16x16x32_bf16(
                        af[m][kk], bfr[n][kk], acc[m][n], 0, 0, 0);

        if (t + 1 < NT) {
            if (t + 2 < NT) wait_vmcnt<L>();
            else            wait_vmcnt<0>();
            __builtin_amdgcn_s_barrier();
        }
    }

    #pragma unroll
    for (int m = 0; m < MF; ++m) {
        int row0 = bm + wr + m * 16 + g * 4;
        #pragma unroll
        for (int n = 0; n < NF; ++n) {
            int col = bn + wc + n * 16 + r16;
            float b = bias[col];
            #pragma unroll
            for (int jj = 0; jj < 4; ++jj)
                out0[(size_t)(row0 + jj) * N + col] = acc[m][n][jj] + b;
        }
    }
}

// ---------------------------------------------------------------------------
// Causal depthwise conv (D_CONV=4) + SiLU, 4 channels x 4 time-rows/thread.
// ---------------------------------------------------------------------------
__global__ __launch_bounds__(256) void conv_silu4_kernel(
    const ushort_t* __restrict__ xssm,
    const float* __restrict__ conv_w,
    const float* __restrict__ conv_b,
    ushort_t* __restrict__ xc)
{
    int idx = blockIdx.x * 256 + threadIdx.x;
    int cg = idx & (D_INNER / 4 - 1);
    int rg = idx >> 9;
    int c  = cg * 4;
    int r4 = rg * 4;
    int s4 = r4 & (SEQ - 1);

    float4 wv[4];
    #pragma unroll
    for (int cc = 0; cc < 4; ++cc)
        wv[cc] = *reinterpret_cast<const float4*>(conv_w + (c + cc) * 4);
    float4 bv = *reinterpret_cast<const float4*>(conv_b + c);
    float bias[4] = {bv.x, bv.y, bv.z, bv.w};

    float xin[7][4];
    #pragma unroll
    for (int rr = 0; rr < 7; ++rr) {
        if (s4 > 0 || rr >= 3) {
            ushort4 v = *reinterpret_cast<const ushort4*>(xssm + (size_t)(r4 + rr - 3) * D_INNER + c);
            xin[rr][0] = bf2f(v.x); xin[rr][1] = bf2f(v.y);
            xin[rr][2] = bf2f(v.z); xin[rr][3] = bf2f(v.w);
        } else {
            xin[rr][0] = xin[rr][1] = xin[rr][2] = xin[rr][3] = 0.f;
        }
    }

    #pragma unroll
    for (int i = 0; i < 4; ++i) {
        float acc[4] = {bias[0], bias[1], bias[2], bias[3]};
        #pragma unroll
        for (int dt = 0; dt < 4; ++dt) {
            int rr = i + 3 - dt;
            acc[0] += (&wv[0].x)[3 - dt] * xin[rr][0];
            acc[1] += (&wv[1].x)[3 - dt] * xin[rr][1];
            acc[2] += (&wv[2].x)[3 - dt] * xin[rr][2];
            acc[3] += (&wv[3].x)[3 - dt] * xin[rr][3];
        }
        ushort4 h;
        h.x = f2bf(silu_f(acc[0]));
        h.y = f2bf(silu_f(acc[1]));
        h.z = f2bf(silu_f(acc[2]));
        h.w = f2bf(silu_f(acc[3]));
        *reinterpret_cast<ushort4*>(xc + (size_t)(r4 + i) * D_INNER + c) = h;
    }
}

// ---------------------------------------------------------------------------
// XB = xconv (4096,2048) @ B(64,2048)^T -> (4096,64), bf16 MFMA.
// ---------------------------------------------------------------------------
#define BK 32
__global__ __launch_bounds__(128) void xb_mfma(
    const ushort_t* __restrict__ xc, const ushort_t* __restrict__ Bw,
    float* __restrict__ xb)
{
    using bf16x8 = __attribute__((ext_vector_type(8))) short;
    using f32x4  = __attribute__((ext_vector_type(4))) float;

    __shared__ ushort_t As[32 * BK];
    __shared__ ushort_t Bs[64 * BK];

    const int tid  = threadIdx.x;
    const int lane = tid & 63;
    const int wid  = tid >> 6;
    const int bm   = blockIdx.x * 32;
    const int r16  = lane & 15;
    const int g    = lane >> 4;
    const int srow = lane >> 2;
    const int scol = (lane & 3) * 8;

    f32x4 acc[4] = {};

    for (int k0 = 0; k0 < D_INNER; k0 += BK) {
        const ushort_t* ga = xc + (size_t)(bm + 16 * wid + srow) * D_INNER + k0 + scol;
        __builtin_amdgcn_global_load_lds((gvoid_t*)ga, (lvoid_t*)(As + wid * 512), 16, 0, 0);
        #pragma unroll
        for (int ii = 0; ii < 2; ++ii) {
            int i = wid * 2 + ii;
            const ushort_t* gb = Bw + (size_t)(16 * i + srow) * D_INNER + k0 + scol;
            __builtin_amdgcn_global_load_lds((gvoid_t*)gb, (lvoid_t*)(Bs + i * 512), 16, 0, 0);
        }
        __syncthreads();

        bf16x8 a = *reinterpret_cast<const bf16x8*>(&As[(wid * 16 + r16) * BK + g * 8]);
        #pragma unroll
        for (int n = 0; n < 4; ++n) {
            bf16x8 bv = *reinterpret_cast<const bf16x8*>(&Bs[(n * 16 + r16) * BK + g * 8]);
            acc[n] = __builtin_amdgcn_mfma_f32_16x16x32_bf16(a, bv, acc[n], 0, 0, 0);
        }
        __syncthreads();
    }

    #pragma unroll
    for (int n = 0; n < 4; ++n) {
        int col  = n * 16 + r16;
        int row0 = bm + wid * 16 + g * 4;
        #pragma unroll
        for (int jj = 0; jj < 4; ++jj)
            xb[(size_t)(row0 + jj) * D_STATE + col] = acc[n][jj];
    }
}

// ---------------------------------------------------------------------------
// Speculative chunked tanh scan (overlap-save), C=W=32.  Emits bf16 H.
// ---------------------------------------------------------------------------
#define SCAN_C 32
#define SCAN_W 32
#define NCHUNK (SEQ / SCAN_C)   // 64

__global__ __launch_bounds__(64) void scan_kernel(const float* __restrict__ xb,
                                                  const float* __restrict__ A,
                                                  ushort_t* __restrict__ hall)
{
    using f32x4 = __attribute__((ext_vector_type(4))) float;

    __shared__ float xs[(SCAN_C + SCAN_W) * D_STATE];   // 16 KB
    __shared__ float hs[D_STATE];

    const int blk = blockIdx.x;
    const int b = blk >> 6;
    const int c = blk & (NCHUNK - 1);
    const int j = threadIdx.x;

    const int t0     = (c == 0) ? 0 : (c * SCAN_C - SCAN_W);
    const int warm   = c * SCAN_C - t0;        // 0 or 32
    const int nsteps = warm + SCAN_C;          // 32 or 64

    f32x4 areg[16];
    {
        const f32x4* arow = reinterpret_cast<const f32x4*>(A + j * D_STATE);
        #pragma unroll
        for (int q = 0; q < 16; ++q) areg[q] = arow[q];
    }

    const float* src = xb   + ((size_t)b * SEQ + t0) * D_STATE;
    ushort_t*    dst = hall + ((size_t)b * SEQ + c * SCAN_C) * D_STATE;

    const int nld = nsteps * D_STATE / 256;
    for (int i = 0; i < nld; ++i)
        __builtin_amdgcn_global_load_lds((gvoid_t*)(src + i * 256 + j * 4),
                                         (lvoid_t*)(&xs[i * 256]), 16, 0, 0);
    asm volatile("s_waitcnt vmcnt(0)" ::: "memory");

    hs[j] = 0.f;
    float h = 0.f;
    const f32x4* hp = reinterpret_cast<const f32x4*>(hs);

#define SCAN_STEP(t)                                                     \
    {                                                                    \
        float xv = xs[(t) * D_STATE + j];                                \
        f32x4 a0 = {xv, 0.f, 0.f, 0.f}, a1 = {0.f, 0.f, 0.f, 0.f};      \
        _Pragma("unroll")                                                \
        for (int q = 0; q < 16; q += 2) {                                \
            a0 += areg[q + 0] * hp[q + 0];                               \
            a1 += areg[q + 1] * hp[q + 1];                               \
        }                                                                \
        f32x4 s4 = a0 + a1;                                              \
        float s = (s4[0] + s4[1]) + (s4[2] + s4[3]);                     \
        float e = __expf(2.f * s);                                       \
        h = 1.f - 2.f * __builtin_amdgcn_rcpf(e + 1.f);                  \
        hs[j] = h;                                                       \
    }

    for (int t = 0; t < warm; ++t) {
        SCAN_STEP(t);
    }
    for (int t = warm; t < nsteps; ++t) {
        SCAN_STEP(t);
        dst[(size_t)(t - warm) * D_STATE + j] = f2bf(h);
    }
#undef SCAN_STEP
}

// ---------------------------------------------------------------------------
// ymul via MFMA: Y = H(4096x64) @ C(2048x64)^T, fused epilogue (r16 proven).
// ---------------------------------------------------------------------------
__global__ __launch_bounds__(256) void ymul_mfma(
    const ushort_t* __restrict__ Hbf,
    const ushort_t* __restrict__ Cbf,
    const float* __restrict__ Dv,
    const ushort_t* __restrict__ xc,
    const ushort_t* __restrict__ xg,
    ushort_t* __restrict__ xout)
{
    using bf16x8 = __attribute__((ext_vector_type(8))) short;
    using f32x4  = __attribute__((ext_vector_type(4))) float;

    constexpr int ARB  = 8;
    constexpr int ABLK = 16;
    constexpr int NBLK = 32;

    __shared__ ushort_t Tb[NBLK * 512];   // 32 KB

    const int tid  = threadIdx.x;
    const int lane = tid & 63;
    const int wid  = tid >> 6;
    const int bm   = blockIdx.y * 128;
    const int bn   = blockIdx.x * 128;
    const int wr   = (wid >> 1) * 64;
    const int wc   = (wid & 1) * 64;
    const int r16  = lane & 15;
    const int g    = lane >> 4;
    const int srow = lane >> 2;
    const int scg  = ((lane & 3) ^ (srow & 3)) * 8;
    const int rg   = (g ^ (r16 & 3)) * 8;

    #pragma unroll
    for (int i = wid; i < NBLK; i += 4) {
        const ushort_t* gsrc;
        if (i < ABLK) {
            int kh = i / ARB, rb = i % ARB;
            gsrc = Hbf + (size_t)(bm + 16 * rb + srow) * D_STATE + kh * 32 + scg;
        } else {
            int j = i - ABLK;
            int kh = j / ARB, rb = j % ARB;
            gsrc = Cbf + (size_t)(bn + 16 * rb + srow) * D_STATE + kh * 32 + scg;
        }
        __builtin_amdgcn_global_load_lds((gvoid_t*)gsrc, (lvoid_t*)(&Tb[i * 512]), 16, 0, 0);
    }
    __syncthreads();

    f32x4 acc[4][4] = {};
    bf16x8 af[4][2], bfr[4][2];
    #pragma unroll
    for (int kk = 0; kk < 2; ++kk) {
        #pragma unroll
        for (int m = 0; m < 4; ++m)
            af[m][kk] = *reinterpret_cast<const bf16x8*>(
                &Tb[(kk * ARB + (wr >> 4) + m) * 512 + r16 * 32 + rg]);
        #pragma unroll
        for (int n = 0; n < 4; ++n)
            bfr[n][kk] = *reinterpret_cast<const bf16x8*>(
                &Tb[(ABLK + kk * ARB + (wc >> 4) + n) * 512 + r16 * 32 + rg]);
    }
    #pragma unroll
    for (int kk = 0; kk < 2; ++kk)
        #pragma unroll
        for (int m = 0; m < 4; ++m)
            #pragma unroll
            for (int n = 0; n < 4; ++n)
                acc[m][n] = __builtin_amdgcn_mfma_f32_16x16x32_bf16(
                    af[m][kk], bfr[n][kk], acc[m][n], 0, 0, 0);

    #pragma unroll
    for (int m = 0; m < 4; ++m) {
        int row0 = bm + wr + m * 16 + g * 4;
        #pragma unroll
        for (int n = 0; n < 4; ++n) {
            int col = bn + wc + n * 16 + r16;
            float dv = Dv[col];
            #pragma unroll
            for (int jj = 0; jj < 4; ++jj) {
                size_t idx = (size_t)(row0 + jj) * D_INNER + col;
                float y = acc[m][n][jj] + bf2f(xc[idx]) * dv;
                xout[idx] = f2bf(y * bf2f(xg[idx]));
            }
        }
    }
}

// ---------------------------------------------------------------------------
extern "C" void kernel_launch(void* const* d_in, const int* in_sizes, int n_in,
                              void* d_out, int out_size, void* d_ws, size_t ws_size,
                              hipStream_t stream)
{
    const float* x          = (const float*)d_in[0];
    const float* in_proj_w  = (const float*)d_in[1];
    const float* in_proj_b  = (const float*)d_in[2];
    const float* conv_w     = (const float*)d_in[3];
    const float* conv_b     = (const float*)d_in[4];
    const float* A          = (const float*)d_in[5];
    const float* B          = (const float*)d_in[6];
    const float* C          = (const float*)d_in[7];
    const float* D          = (const float*)d_in[8];
    const float* out_proj_w = (const float*)d_in[9];
    const float* out_proj_b = (const float*)d_in[10];
    float* out = (float*)d_out;

    char* ws = (char*)d_ws;
    ushort_t* xg_bf   = (ushort_t*)(ws + 0);             // 16,777,216
    ushort_t* xc_bf   = (ushort_t*)(ws + 16777216);      // 16,777,216
    ushort_t* xssm_bf = (ushort_t*)(ws + 33554432);      // 16,777,216 (dead after conv)
    ushort_t* x_bf    = (ushort_t*)(ws + 50331648);      //  8,388,608 (dead after in_proj)
    ushort_t* w1_bf   = (ushort_t*)(ws + 58720256);      //  8,388,608 (dead after in_proj)
    ushort_t* xout_bf = (ushort_t*)(ws + 50331648);      // 16,777,216 (reuses x_bf+w1_bf)
    ushort_t* w2_bf   = (ushort_t*)(ws + 67108864);      //  4,194,304
    ushort_t* B_bf    = (ushort_t*)(ws + 71303168);      //    262,144
    float*    xb      = (float*)(ws + 71565312);         //  1,048,576
    ushort_t* hall_bf = (ushort_t*)(ws + 72613888);      //    524,288
    ushort_t* C_bf    = (ushort_t*)(ws + 73138176);      //    262,144

    // 1. all f32 -> bf16 conversions, one launch (x, w1, w2, B, C)
    {
        int b0 = NROWS * D_MODEL / 1024;           // 4096
        int b1 = 2 * D_INNER * D_MODEL / 1024;     // 4096
        int b2 = D_MODEL * D_INNER / 1024;         // 2048
        int b3 = D_STATE * D_INNER / 1024;         // 128
        int b4 = D_INNER * D_STATE / 1024;         // 128
        cvt5_kernel<<<b0 + b1 + b2 + b3 + b4, 256, 0, stream>>>(
            x, x_bf, b0, in_proj_w, w1_bf, b1, out_proj_w, w2_bf, b2,
            B, B_bf, b3, C, C_bf, b4);
    }
    // 2. in_proj GEMM (8-wave 256x128 depth-2, 2-D raster — measured best)
    {
        dim3 grid(2 * D_INNER / 128, NROWS / 256);
        gemm_pipe8_inproj<<<grid, 512, 0, stream>>>(x_bf, w1_bf, in_proj_b,
                                                    xssm_bf, xg_bf, D_MODEL);
    }
    // 3. conv + silu -> bf16 (4 rows/thread)
    conv_silu4_kernel<<<NROWS * D_INNER / 16 / 256, 256, 0, stream>>>(xssm_bf, conv_w, conv_b, xc_bf);
    // 4. XB via bf16 MFMA
    xb_mfma<<<NROWS / 32, 128, 0, stream>>>(xc_bf, B_bf, xb);
    // 5. speculative chunked scan (C=W=32) -> bf16 H
    scan_kernel<<<BATCH * NCHUNK, 64, 0, stream>>>(xb, A, hall_bf);
    // 6. ymul via MFMA (fused D-skip + gate) -> bf16 x_out
    {
        dim3 grid(D_INNER / 128, NROWS / 128);
        ymul_mfma<<<grid, 256, 0, stream>>>(hall_bf, C_bf, D, xc_bf, xg_bf, xout_bf);
    }
    // 7. out_proj GEMM (256-thread 128x64 KH=2, XCD-chunked — measured best)
    gemm_pipe<128, 64, 2><<<(NROWS / 128) * (D_MODEL / 64), 256, 0, stream>>>(
        xout_bf, w2_bf, out_proj_b, out, NROWS, D_MODEL, D_INNER);
}

// Round 22
// 132.613 us; speedup vs baseline: 1.9704x; 1.1169x over previous
//
#include <hip/hip_runtime.h>
#include <math.h>

#define D_MODEL 1024
#define D_INNER 2048
#define D_STATE 64
#define SEQ     2048
#define BATCH   2
#define NROWS   (BATCH*SEQ)   // 4096

typedef unsigned short ushort_t;
typedef unsigned int uint_t;

__device__ __forceinline__ float silu_f(float x) { return x / (1.f + __expf(-x)); }
__device__ __forceinline__ ushort_t f2bf(float f) {
    uint_t u = __float_as_uint(f);
    uint_t r = (u + 0x7FFFu + ((u >> 16) & 1u)) >> 16;   // RNE
    return (ushort_t)r;
}
__device__ __forceinline__ float bf2f(ushort_t u) {
    return __uint_as_float(((uint_t)u) << 16);
}

typedef __attribute__((address_space(1))) const void gvoid_t;
typedef __attribute__((address_space(3))) void lvoid_t;

template<int N> __device__ __forceinline__ void wait_vmcnt() {
    if constexpr (N == 0)      asm volatile("s_waitcnt vmcnt(0)" ::: "memory");
    else if constexpr (N == 3) asm volatile("s_waitcnt vmcnt(3)" ::: "memory");
    else if constexpr (N == 6) asm volatile("s_waitcnt vmcnt(6)" ::: "memory");
    else static_assert(N == 0, "unsupported vmcnt");
}

// ---------------------------------------------------------------------------
// Batched f32 -> bf16 conversion: 5 (src,dst) ranges in one launch.
// ---------------------------------------------------------------------------
__global__ __launch_bounds__(256) void cvt5_kernel(
    const float* __restrict__ s0, ushort_t* __restrict__ d0, int b0,
    const float* __restrict__ s1, ushort_t* __restrict__ d1, int b1,
    const float* __restrict__ s2, ushort_t* __restrict__ d2, int b2,
    const float* __restrict__ s3, ushort_t* __restrict__ d3, int b3,
    const float* __restrict__ s4, ushort_t* __restrict__ d4, int b4)
{
    int blk = blockIdx.x;
    const float* s; ushort_t* d;
    if (blk < b0)                    { s = s0; d = d0; }
    else if (blk < b0 + b1)          { s = s1; d = d1; blk -= b0; }
    else if (blk < b0 + b1 + b2)     { s = s2; d = d2; blk -= b0 + b1; }
    else if (blk < b0 + b1 + b2 + b3){ s = s3; d = d3; blk -= b0 + b1 + b2; }
    else                             { s = s4; d = d4; blk -= b0 + b1 + b2 + b3; }
    int i = (blk * 256 + threadIdx.x) * 4;
    float4 v = *reinterpret_cast<const float4*>(s + i);
    ushort4 o;
    o.x = f2bf(v.x); o.y = f2bf(v.y); o.z = f2bf(v.z); o.w = f2bf(v.w);
    *reinterpret_cast<ushort4*>(d + i) = o;
}

// ---------------------------------------------------------------------------
// in_proj GEMM: 8-wave 256x128 depth-2, 2-D raster (measured-best).
// ---------------------------------------------------------------------------
__global__ __launch_bounds__(512, 4) void gemm_pipe8_inproj(
    const ushort_t* __restrict__ Abf, const ushort_t* __restrict__ Wbf,
    const float* __restrict__ bias,
    ushort_t* __restrict__ out_x, ushort_t* __restrict__ out_g, int K)
{
    using bf16x8 = __attribute__((ext_vector_type(8))) short;
    using f32x4  = __attribute__((ext_vector_type(4))) float;

    constexpr int BMt  = 256, BNt = 128, BKt = 32;
    constexpr int ABLK = BMt / 16;            // 16
    constexpr int NBLK = (BMt + BNt) / 16;    // 24
    constexpr int TILE = (BMt + BNt) * BKt;   // 24KB
    constexpr int L    = NBLK / 8;            // 3

    __shared__ ushort_t buf[2][TILE];

    const int tid  = threadIdx.x;
    const int lane = tid & 63;
    const int wid  = tid >> 6;
    const int bm   = blockIdx.y * BMt;
    const int bn   = blockIdx.x * BNt;
    const int wr   = (wid >> 1) * 64;
    const int wc   = (wid & 1) * 64;
    const int r16  = lane & 15;
    const int g    = lane >> 4;
    const int srow = lane >> 2;
    const int scg  = ((lane & 3) ^ (srow & 3)) * 8;
    const int rg   = (g ^ (r16 & 3)) * 8;

    f32x4 acc[4][4] = {};

    auto stage = [&](int p, int k0) {
        #pragma unroll
        for (int i = wid; i < NBLK; i += 8) {
            const ushort_t* gsrc;
            if (i < ABLK)
                gsrc = Abf + (size_t)(bm + 16 * i + srow) * K + k0 + scg;
            else
                gsrc = Wbf + (size_t)(bn + 16 * (i - ABLK) + srow) * K + k0 + scg;
            __builtin_amdgcn_global_load_lds((gvoid_t*)gsrc, (lvoid_t*)(&buf[p][i * 512]), 16, 0, 0);
        }
    };

    const int NT = K / BKt;
    stage(0, 0);
    stage(1, BKt);
    wait_vmcnt<L>();
    __builtin_amdgcn_s_barrier();

    for (int t = 0; t < NT; ++t) {
        const ushort_t* Tb = &buf[t & 1][0];
        bf16x8 af[4], bfr[4];
        #pragma unroll
        for (int m = 0; m < 4; ++m)
            af[m] = *reinterpret_cast<const bf16x8*>(
                &Tb[((wr >> 4) + m) * 512 + r16 * 32 + rg]);
        #pragma unroll
        for (int n = 0; n < 4; ++n)
            bfr[n] = *reinterpret_cast<const bf16x8*>(
                &Tb[(ABLK + (wc >> 4) + n) * 512 + r16 * 32 + rg]);

        asm volatile("s_waitcnt lgkmcnt(0)" ::: "memory");
        __builtin_amdgcn_s_barrier();

        if (t + 2 < NT) stage(t & 1, (t + 2) * BKt);

        #pragma unroll
        for (int m = 0; m < 4; ++m)
            #pragma unroll
            for (int n = 0; n < 4; ++n)
                acc[m][n] = __builtin_amdgcn_mfma_f32_16x16x32_bf16(af[m], bfr[n], acc[m][n], 0, 0, 0);

        if (t + 1 < NT) {
            if (t + 2 < NT) wait_vmcnt<L>();
            else            wait_vmcnt<0>();
            __builtin_amdgcn_s_barrier();
        }
    }

    #pragma unroll
    for (int m = 0; m < 4; ++m) {
        int row0 = bm + wr + m * 16 + g * 4;
        #pragma unroll
        for (int n = 0; n < 4; ++n) {
            int col = bn + wc + n * 16 + r16;
            float b = bias[col];
            if (col < D_INNER) {
                #pragma unroll
                for (int jj = 0; jj < 4; ++jj)
                    out_x[(size_t)(row0 + jj) * D_INNER + col] = f2bf(acc[m][n][jj] + b);
            } else {
                int c2 = col - D_INNER;
                #pragma unroll
                for (int jj = 0; jj < 4; ++jj)
                    out_g[(size_t)(row0 + jj) * D_INNER + c2] = f2bf(silu_f(acc[m][n][jj] + b));
            }
        }
    }
}

// ---------------------------------------------------------------------------
// out_proj GEMM: 256-thread depth-2, KH=2, XCD-chunk swizzle (measured-best).
// ---------------------------------------------------------------------------
template <int BMt, int BNt, int KH>
__global__ __launch_bounds__(256) void gemm_pipe(
    const ushort_t* __restrict__ Abf, const ushort_t* __restrict__ Wbf,
    const float* __restrict__ bias,
    float* __restrict__ out0, int M, int N, int K)
{
    using bf16x8 = __attribute__((ext_vector_type(8))) short;
    using f32x4  = __attribute__((ext_vector_type(4))) float;

    constexpr int BKt  = 32 * KH;
    constexpr int MF   = BMt / 32;
    constexpr int NF   = BNt / 32;
    constexpr int ARB  = BMt / 16;
    constexpr int BRB  = BNt / 16;
    constexpr int ABLK = ARB * KH;
    constexpr int NBLK = (ARB + BRB) * KH;
    constexpr int TILE = (BMt + BNt) * BKt;
    constexpr int L    = NBLK / 4;

    __shared__ ushort_t buf[2][TILE];

    const int tid  = threadIdx.x;
    const int lane = tid & 63;
    const int wid  = tid >> 6;

    const int nbn  = N / BNt;
    const int bid  = blockIdx.x;
    const int nb   = (M / BMt) * nbn;
    const int cpx  = nb / 8;
    const int flat = (bid & 7) * cpx + (bid >> 3);
    const int bm   = (flat / nbn) * BMt;
    const int bn   = (flat % nbn) * BNt;

    const int wr   = (wid >> 1) * (BMt / 2);
    const int wc   = (wid & 1) * (BNt / 2);
    const int r16  = lane & 15;
    const int g    = lane >> 4;
    const int srow = lane >> 2;
    const int scg  = ((lane & 3) ^ (srow & 3)) * 8;
    const int rg   = (g ^ (r16 & 3)) * 8;

    f32x4 acc[MF][NF] = {};

    auto stage = [&](int p, int k0) {
        #pragma unroll
        for (int i = wid; i < NBLK; i += 4) {
            const ushort_t* gsrc;
            if (i < ABLK) {
                int kh = i / ARB, rb = i % ARB;
                gsrc = Abf + (size_t)(bm + 16 * rb + srow) * K + k0 + kh * 32 + scg;
            } else {
                int j = i - ABLK;
                int kh = j / BRB, rb = j % BRB;
                gsrc = Wbf + (size_t)(bn + 16 * rb + srow) * K + k0 + kh * 32 + scg;
            }
            __builtin_amdgcn_global_load_lds((gvoid_t*)gsrc, (lvoid_t*)(&buf[p][i * 512]), 16, 0, 0);
        }
    };

    const int NT = K / BKt;
    stage(0, 0);
    stage(1, BKt);
    wait_vmcnt<L>();
    __builtin_amdgcn_s_barrier();

    for (int t = 0; t < NT; ++t) {
        const ushort_t* Tb = &buf[t & 1][0];
        bf16x8 af[MF][KH], bfr[NF][KH];
        #pragma unroll
        for (int kk = 0; kk < KH; ++kk) {
            #pragma unroll
            for (int m = 0; m < MF; ++m)
                af[m][kk] = *reinterpret_cast<const bf16x8*>(
                    &Tb[(kk * ARB + (wr >> 4) + m) * 512 + r16 * 32 + rg]);
            #pragma unroll
            for (int n = 0; n < NF; ++n)
                bfr[n][kk] = *reinterpret_cast<const bf16x8*>(
                    &Tb[(ABLK + kk * BRB + (wc >> 4) + n) * 512 + r16 * 32 + rg]);
        }

        asm volatile("s_waitcnt lgkmcnt(0)" ::: "memory");
        __builtin_amdgcn_s_barrier();

        if (t + 2 < NT) stage(t & 1, (t + 2) * BKt);

        #pragma unroll
        for (int kk = 0; kk < KH; ++kk)
            #pragma unroll
            for (int m = 0; m < MF; ++m)
                #pragma unroll
                for (int n = 0; n < NF; ++n)
                    acc[m][n] = __builtin_amdgcn_mfma_f32_16x16x32_bf16(
                        af[m][kk], bfr[n][kk], acc[m][n], 0, 0, 0);

        if (t + 1 < NT) {
            if (t + 2 < NT) wait_vmcnt<L>();
            else            wait_vmcnt<0>();
            __builtin_amdgcn_s_barrier();
        }
    }

    #pragma unroll
    for (int m = 0; m < MF; ++m) {
        int row0 = bm + wr + m * 16 + g * 4;
        #pragma unroll
        for (int n = 0; n < NF; ++n) {
            int col = bn + wc + n * 16 + r16;
            float b = bias[col];
            #pragma unroll
            for (int jj = 0; jj < 4; ++jj)
                out0[(size_t)(row0 + jj) * N + col] = acc[m][n][jj] + b;
        }
    }
}

// ---------------------------------------------------------------------------
// Causal depthwise conv (D_CONV=4) + SiLU, 4 channels x 4 time-rows/thread.
// ---------------------------------------------------------------------------
__global__ __launch_bounds__(256) void conv_silu4_kernel(
    const ushort_t* __restrict__ xssm,
    const float* __restrict__ conv_w,
    const float* __restrict__ conv_b,
    ushort_t* __restrict__ xc)
{
    int idx = blockIdx.x * 256 + threadIdx.x;
    int cg = idx & (D_INNER / 4 - 1);
    int rg = idx >> 9;
    int c  = cg * 4;
    int r4 = rg * 4;
    int s4 = r4 & (SEQ - 1);

    float4 wv[4];
    #pragma unroll
    for (int cc = 0; cc < 4; ++cc)
        wv[cc] = *reinterpret_cast<const float4*>(conv_w + (c + cc) * 4);
    float4 bv = *reinterpret_cast<const float4*>(conv_b + c);
    float bias[4] = {bv.x, bv.y, bv.z, bv.w};

    float xin[7][4];
    #pragma unroll
    for (int rr = 0; rr < 7; ++rr) {
        if (s4 > 0 || rr >= 3) {
            ushort4 v = *reinterpret_cast<const ushort4*>(xssm + (size_t)(r4 + rr - 3) * D_INNER + c);
            xin[rr][0] = bf2f(v.x); xin[rr][1] = bf2f(v.y);
            xin[rr][2] = bf2f(v.z); xin[rr][3] = bf2f(v.w);
        } else {
            xin[rr][0] = xin[rr][1] = xin[rr][2] = xin[rr][3] = 0.f;
        }
    }

    #pragma unroll
    for (int i = 0; i < 4; ++i) {
        float acc[4] = {bias[0], bias[1], bias[2], bias[3]};
        #pragma unroll
        for (int dt = 0; dt < 4; ++dt) {
            int rr = i + 3 - dt;
            acc[0] += (&wv[0].x)[3 - dt] * xin[rr][0];
            acc[1] += (&wv[1].x)[3 - dt] * xin[rr][1];
            acc[2] += (&wv[2].x)[3 - dt] * xin[rr][2];
            acc[3] += (&wv[3].x)[3 - dt] * xin[rr][3];
        }
        ushort4 h;
        h.x = f2bf(silu_f(acc[0]));
        h.y = f2bf(silu_f(acc[1]));
        h.z = f2bf(silu_f(acc[2]));
        h.w = f2bf(silu_f(acc[3]));
        *reinterpret_cast<ushort4*>(xc + (size_t)(r4 + i) * D_INNER + c) = h;
    }
}

// ---------------------------------------------------------------------------
// XB split-K: partial[kh] = xconv(.,kh*1024:+1024) @ B^T  -> (4096,64) f32.
// 256 blocks (128 row-blocks x 2 k-halves), 128 threads.  Sum happens in
// the scan's staging (f32 add, ~1ulp reorder).
// ---------------------------------------------------------------------------
#define BK 32
__global__ __launch_bounds__(128) void xb_mfma(
    const ushort_t* __restrict__ xc, const ushort_t* __restrict__ Bw,
    float* __restrict__ xbp)
{
    using bf16x8 = __attribute__((ext_vector_type(8))) short;
    using f32x4  = __attribute__((ext_vector_type(4))) float;

    __shared__ ushort_t As[32 * BK];
    __shared__ ushort_t Bs[64 * BK];

    const int tid  = threadIdx.x;
    const int lane = tid & 63;
    const int wid  = tid >> 6;
    const int kh   = blockIdx.x & 1;
    const int bm   = (blockIdx.x >> 1) * 32;
    const int kb   = kh * (D_INNER / 2);
    const int r16  = lane & 15;
    const int g    = lane >> 4;
    const int srow = lane >> 2;
    const int scol = (lane & 3) * 8;

    float* xb = xbp + (size_t)kh * NROWS * D_STATE;

    f32x4 acc[4] = {};

    for (int k0 = kb; k0 < kb + D_INNER / 2; k0 += BK) {
        const ushort_t* ga = xc + (size_t)(bm + 16 * wid + srow) * D_INNER + k0 + scol;
        __builtin_amdgcn_global_load_lds((gvoid_t*)ga, (lvoid_t*)(As + wid * 512), 16, 0, 0);
        #pragma unroll
        for (int ii = 0; ii < 2; ++ii) {
            int i = wid * 2 + ii;
            const ushort_t* gb = Bw + (size_t)(16 * i + srow) * D_INNER + k0 + scol;
            __builtin_amdgcn_global_load_lds((gvoid_t*)gb, (lvoid_t*)(Bs + i * 512), 16, 0, 0);
        }
        __syncthreads();

        bf16x8 a = *reinterpret_cast<const bf16x8*>(&As[(wid * 16 + r16) * BK + g * 8]);
        #pragma unroll
        for (int n = 0; n < 4; ++n) {
            bf16x8 bv = *reinterpret_cast<const bf16x8*>(&Bs[(n * 16 + r16) * BK + g * 8]);
            acc[n] = __builtin_amdgcn_mfma_f32_16x16x32_bf16(a, bv, acc[n], 0, 0, 0);
        }
        __syncthreads();
    }

    #pragma unroll
    for (int n = 0; n < 4; ++n) {
        int col  = n * 16 + r16;
        int row0 = bm + wid * 16 + g * 4;
        #pragma unroll
        for (int jj = 0; jj < 4; ++jj)
            xb[(size_t)(row0 + jj) * D_STATE + col] = acc[n][jj];
    }
}

// ---------------------------------------------------------------------------
// Speculative chunked tanh scan (overlap-save), C=W=16 (32 serial steps).
// Reads TWO split-K partials, sums during the step.  Emits bf16 H.
// ---------------------------------------------------------------------------
#define SCAN_C 16
#define SCAN_W 16
#define NCHUNK (SEQ / SCAN_C)   // 128

__global__ __launch_bounds__(64) void scan_kernel(const float* __restrict__ xb0,
                                                  const float* __restrict__ xb1,
                                                  const float* __restrict__ A,
                                                  ushort_t* __restrict__ hall)
{
    using f32x4 = __attribute__((ext_vector_type(4))) float;

    __shared__ float xs0[(SCAN_C + SCAN_W) * D_STATE];   // 8 KB
    __shared__ float xs1[(SCAN_C + SCAN_W) * D_STATE];   // 8 KB
    __shared__ float hs[D_STATE];

    const int blk = blockIdx.x;
    const int b = blk >> 7;          // / NCHUNK
    const int c = blk & (NCHUNK - 1);
    const int j = threadIdx.x;

    const int t0     = (c == 0) ? 0 : (c * SCAN_C - SCAN_W);
    const int warm   = c * SCAN_C - t0;        // 0 or 16
    const int nsteps = warm + SCAN_C;          // 16 or 32

    f32x4 areg[16];
    {
        const f32x4* arow = reinterpret_cast<const f32x4*>(A + j * D_STATE);
        #pragma unroll
        for (int q = 0; q < 16; ++q) areg[q] = arow[q];
    }

    const float* src0 = xb0 + ((size_t)b * SEQ + t0) * D_STATE;
    const float* src1 = xb1 + ((size_t)b * SEQ + t0) * D_STATE;
    ushort_t*    dst  = hall + ((size_t)b * SEQ + c * SCAN_C) * D_STATE;

    const int nld = nsteps * D_STATE / 256;    // 4 or 8 x 1KB per partial
    for (int i = 0; i < nld; ++i) {
        __builtin_amdgcn_global_load_lds((gvoid_t*)(src0 + i * 256 + j * 4),
                                         (lvoid_t*)(&xs0[i * 256]), 16, 0, 0);
        __builtin_amdgcn_global_load_lds((gvoid_t*)(src1 + i * 256 + j * 4),
                                         (lvoid_t*)(&xs1[i * 256]), 16, 0, 0);
    }
    asm volatile("s_waitcnt vmcnt(0)" ::: "memory");

    hs[j] = 0.f;
    float h = 0.f;
    const f32x4* hp = reinterpret_cast<const f32x4*>(hs);

#define SCAN_STEP(t)                                                     \
    {                                                                    \
        float xv = xs0[(t) * D_STATE + j] + xs1[(t) * D_STATE + j];      \
        f32x4 a0 = {xv, 0.f, 0.f, 0.f}, a1 = {0.f, 0.f, 0.f, 0.f};      \
        _Pragma("unroll")                                                \
        for (int q = 0; q < 16; q += 2) {                                \
            a0 += areg[q + 0] * hp[q + 0];                               \
            a1 += areg[q + 1] * hp[q + 1];                               \
        }                                                                \
        f32x4 s4 = a0 + a1;                                              \
        float s = (s4[0] + s4[1]) + (s4[2] + s4[3]);                     \
        float e = __expf(2.f * s);                                       \
        h = 1.f - 2.f * __builtin_amdgcn_rcpf(e + 1.f);                  \
        hs[j] = h;                                                       \
    }

    for (int t = 0; t < warm; ++t) {
        SCAN_STEP(t);
    }
    for (int t = warm; t < nsteps; ++t) {
        SCAN_STEP(t);
        dst[(size_t)(t - warm) * D_STATE + j] = f2bf(h);
    }
#undef SCAN_STEP
}

// ---------------------------------------------------------------------------
// ymul via MFMA: Y = H(4096x64) @ C(2048x64)^T, fused epilogue (proven).
// ---------------------------------------------------------------------------
__global__ __launch_bounds__(256) void ymul_mfma(
    const ushort_t* __restrict__ Hbf,
    const ushort_t* __restrict__ Cbf,
    const float* __restrict__ Dv,
    const ushort_t* __restrict__ xc,
    const ushort_t* __restrict__ xg,
    ushort_t* __restrict__ xout)
{
    using bf16x8 = __attribute__((ext_vector_type(8))) short;
    using f32x4  = __attribute__((ext_vector_type(4))) float;

    constexpr int ARB  = 8;
    constexpr int ABLK = 16;
    constexpr int NBLK = 32;

    __shared__ ushort_t Tb[NBLK * 512];   // 32 KB

    const int tid  = threadIdx.x;
    const int lane = tid & 63;
    const int wid  = tid >> 6;
    const int bm   = blockIdx.y * 128;
    const int bn   = blockIdx.x * 128;
    const int wr   = (wid >> 1) * 64;
    const int wc   = (wid & 1) * 64;
    const int r16  = lane & 15;
    const int g    = lane >> 4;
    const int srow = lane >> 2;
    const int scg  = ((lane & 3) ^ (srow & 3)) * 8;
    const int rg   = (g ^ (r16 & 3)) * 8;

    #pragma unroll
    for (int i = wid; i < NBLK; i += 4) {
        const ushort_t* gsrc;
        if (i < ABLK) {
            int kh = i / ARB, rb = i % ARB;
            gsrc = Hbf + (size_t)(bm + 16 * rb + srow) * D_STATE + kh * 32 + scg;
        } else {
            int j = i - ABLK;
            int kh = j / ARB, rb = j % ARB;
            gsrc = Cbf + (size_t)(bn + 16 * rb + srow) * D_STATE + kh * 32 + scg;
        }
        __builtin_amdgcn_global_load_lds((gvoid_t*)gsrc, (lvoid_t*)(&Tb[i * 512]), 16, 0, 0);
    }
    __syncthreads();

    f32x4 acc[4][4] = {};
    bf16x8 af[4][2], bfr[4][2];
    #pragma unroll
    for (int kk = 0; kk < 2; ++kk) {
        #pragma unroll
        for (int m = 0; m < 4; ++m)
            af[m][kk] = *reinterpret_cast<const bf16x8*>(
                &Tb[(kk * ARB + (wr >> 4) + m) * 512 + r16 * 32 + rg]);
        #pragma unroll
        for (int n = 0; n < 4; ++n)
            bfr[n][kk] = *reinterpret_cast<const bf16x8*>(
                &Tb[(ABLK + kk * ARB + (wc >> 4) + n) * 512 + r16 * 32 + rg]);
    }
    #pragma unroll
    for (int kk = 0; kk < 2; ++kk)
        #pragma unroll
        for (int m = 0; m < 4; ++m)
            #pragma unroll
            for (int n = 0; n < 4; ++n)
                acc[m][n] = __builtin_amdgcn_mfma_f32_16x16x32_bf16(
                    af[m][kk], bfr[n][kk], acc[m][n], 0, 0, 0);

    #pragma unroll
    for (int m = 0; m < 4; ++m) {
        int row0 = bm + wr + m * 16 + g * 4;
        #pragma unroll
        for (int n = 0; n < 4; ++n) {
            int col = bn + wc + n * 16 + r16;
            float dv = Dv[col];
            #pragma unroll
            for (int jj = 0; jj < 4; ++jj) {
                size_t idx = (size_t)(row0 + jj) * D_INNER + col;
                float y = acc[m][n][jj] + bf2f(xc[idx]) * dv;
                xout[idx] = f2bf(y * bf2f(xg[idx]));
            }
        }
    }
}

// ---------------------------------------------------------------------------
extern "C" void kernel_launch(void* const* d_in, const int* in_sizes, int n_in,
                              void* d_out, int out_size, void* d_ws, size_t ws_size,
                              hipStream_t stream)
{
    const float* x          = (const float*)d_in[0];
    const float* in_proj_w  = (const float*)d_in[1];
    const float* in_proj_b  = (const float*)d_in[2];
    const float* conv_w     = (const float*)d_in[3];
    const float* conv_b     = (const float*)d_in[4];
    const float* A          = (const float*)d_in[5];
    const float* B          = (const float*)d_in[6];
    const float* C          = (const float*)d_in[7];
    const float* D          = (const float*)d_in[8];
    const float* out_proj_w = (const float*)d_in[9];
    const float* out_proj_b = (const float*)d_in[10];
    float* out = (float*)d_out;

    char* ws = (char*)d_ws;
    ushort_t* xg_bf   = (ushort_t*)(ws + 0);             // 16,777,216
    ushort_t* xc_bf   = (ushort_t*)(ws + 16777216);      // 16,777,216
    ushort_t* xssm_bf = (ushort_t*)(ws + 33554432);      // 16,777,216 (dead after conv)
    ushort_t* x_bf    = (ushort_t*)(ws + 50331648);      //  8,388,608 (dead after in_proj)
    ushort_t* w1_bf   = (ushort_t*)(ws + 58720256);      //  8,388,608 (dead after in_proj)
    ushort_t* xout_bf = (ushort_t*)(ws + 50331648);      // 16,777,216 (reuses x_bf+w1_bf)
    ushort_t* w2_bf   = (ushort_t*)(ws + 67108864);      //  4,194,304
    ushort_t* B_bf    = (ushort_t*)(ws + 71303168);      //    262,144
    float*    xb01    = (float*)(ws + 71565312);         //  2,097,152 (2 partials)
    ushort_t* hall_bf = (ushort_t*)(ws + 73662464);      //    524,288
    ushort_t* C_bf    = (ushort_t*)(ws + 74186752);      //    262,144

    // 1. all f32 -> bf16 conversions, one launch (x, w1, w2, B, C)
    {
        int b0 = NROWS * D_MODEL / 1024;           // 4096
        int b1 = 2 * D_INNER * D_MODEL / 1024;     // 4096
        int b2 = D_MODEL * D_INNER / 1024;         // 2048
        int b3 = D_STATE * D_INNER / 1024;         // 128
        int b4 = D_INNER * D_STATE / 1024;         // 128
        cvt5_kernel<<<b0 + b1 + b2 + b3 + b4, 256, 0, stream>>>(
            x, x_bf, b0, in_proj_w, w1_bf, b1, out_proj_w, w2_bf, b2,
            B, B_bf, b3, C, C_bf, b4);
    }
    // 2. in_proj GEMM (8-wave 256x128 depth-2, 2-D raster — measured best)
    {
        dim3 grid(2 * D_INNER / 128, NROWS / 256);
        gemm_pipe8_inproj<<<grid, 512, 0, stream>>>(x_bf, w1_bf, in_proj_b,
                                                    xssm_bf, xg_bf, D_MODEL);
    }
    // 3. conv + silu -> bf16 (4 rows/thread)
    conv_silu4_kernel<<<NROWS * D_INNER / 16 / 256, 256, 0, stream>>>(xssm_bf, conv_w, conv_b, xc_bf);
    // 4. XB via bf16 MFMA, split-K 2-way (256 blocks)
    xb_mfma<<<(NROWS / 32) * 2, 128, 0, stream>>>(xc_bf, B_bf, xb01);
    // 5. speculative chunked scan (C=W=16), sums the two partials -> bf16 H
    scan_kernel<<<BATCH * NCHUNK, 64, 0, stream>>>(
        xb01, xb01 + (size_t)NROWS * D_STATE, A, hall_bf);
    // 6. ymul via MFMA (fused D-skip + gate) -> bf16 x_out
    {
        dim3 grid(D_INNER / 128, NROWS / 128);
        ymul_mfma<<<grid, 256, 0, stream>>>(hall_bf, C_bf, D, xc_bf, xg_bf, xout_bf);
    }
    // 7. out_proj GEMM (256-thread 128x64 KH=2, XCD-chunked — measured best)
    gemm_pipe<128, 64, 2><<<(NROWS / 128) * (D_MODEL / 64), 256, 0, stream>>>(
        xout_bf, w2_bf, out_proj_b, out, NROWS, D_MODEL, D_INNER);
}